// Round 1
// baseline (1044.039 us; speedup 1.0000x reference)
//
#include <hip/hip_runtime.h>

#define N_ROLL   256
#define N_AGENT  64
#define HIDDEN   256
#define CL       0.5f

// One block per (roll, agent) row; 256 threads.
// Phase 1: first wave (64 lanes) does a stable rank-sort of the 64 distances.
// Phase 2: all 256 threads stream 64 output rows (256 floats each) as float4.
__global__ __launch_bounds__(256) void gather_sorted_kernel(
    const float* __restrict__ hid,   // [R*A, H]
    const float* __restrict__ dis,   // [R*A, A]
    float* __restrict__ out)         // [R*A, A, H]
{
    const int row = blockIdx.x;            // r*A + agent
    const int r   = row >> 6;              // roll index
    const int t   = threadIdx.x;

    __shared__ int s_src[N_AGENT];         // source agent per sorted slot; -1 => zero row

    if (t < N_AGENT) {
        const float d = dis[(size_t)row * N_AGENT + t];
        // stable rank across the first 64-lane wave:
        // rank = #{j : d_j < d_i} + #{j < i : d_j == d_i}  (matches stable argsort)
        int rank = 0;
        #pragma unroll
        for (int j = 0; j < N_AGENT; ++j) {
            const float dj = __shfl(d, j, 64);
            rank += (dj < d) || (dj == d && j < t);
        }
        const bool keep = (d < CL) || (rank < 2);
        s_src[rank] = keep ? t : -1;
    }
    __syncthreads();

    const float4* __restrict__ hid4 = reinterpret_cast<const float4*>(hid);
    float4* __restrict__ out4 = reinterpret_cast<float4*>(out);

    const int q = t & 63;                                  // float4 slot within a row (H/4 = 64)
    const size_t out_base = (size_t)row * N_AGENT * (HIDDEN / 4);
    const size_t hid_base = (size_t)r   * N_AGENT * (HIDDEN / 4);

    // 64 rows x 64 float4 = 4096 float4; 256 threads -> 16 iterations, 4 rows per iter
    #pragma unroll
    for (int it = 0; it < 16; ++it) {
        const int a   = it * 4 + (t >> 6);                 // sorted slot
        const int src = s_src[a];
        float4 v = make_float4(0.f, 0.f, 0.f, 0.f);
        if (src >= 0) v = hid4[hid_base + (size_t)src * (HIDDEN / 4) + q];
        out4[out_base + (size_t)a * (HIDDEN / 4) + q] = v;
    }
}

extern "C" void kernel_launch(void* const* d_in, const int* in_sizes, int n_in,
                              void* d_out, int out_size, void* d_ws, size_t ws_size,
                              hipStream_t stream) {
    const float* hid = (const float*)d_in[0];   // [R*A, H] fp32
    const float* dis = (const float*)d_in[1];   // [R*A, A] fp32
    float* out = (float*)d_out;                 // [R*A, A, H] fp32

    dim3 grid(N_ROLL * N_AGENT);
    dim3 block(256);
    gather_sorted_kernel<<<grid, block, 0, stream>>>(hid, dis, out);
}